// Round 9
// baseline (419.252 us; speedup 1.0000x reference)
//
#include <hip/hip_runtime.h>
#include <hip/hip_bf16.h>
#include <stdint.h>

#define S_LEN 512
#define BATCH 512
#define HID   128
#define G3    384
#define EMB   50
#define VOC   50000

// sigmoid(x) = rcp(1 + exp2(x * -log2(e))); tanh(y) = 2*sigmoid(2y)-1.
// W_hh/gxv rows are PRE-SCALED: r,z rows by NL2E, n rows by N2L2E.
#define NL2E  (-1.4426950408889634f)
#define N2L2E (-2.8853900817779268f)

typedef __attribute__((ext_vector_type(8))) short short8;
typedef __attribute__((ext_vector_type(4))) float float4v;

__device__ inline unsigned short f2bf(float f) {
  union { float f; uint32_t u; } v; v.f = f;
  uint32_t u = v.u;
  u += 0x7fffu + ((u >> 16) & 1u);   // RNE
  return (unsigned short)(u >> 16);
}
__device__ inline float bf2f(unsigned short h) {
  union { uint32_t u; float f; } v; v.u = ((uint32_t)h) << 16;
  return v.f;
}
__device__ inline uint32_t fbits(float f) {
  union { float f; uint32_t u; } v; v.f = f; return v.u;
}
__device__ inline float fast_sig(float x) {
  return __builtin_amdgcn_rcpf(1.f + __expf(-x));
}

// ---------------------------------------------------------------------------
// Kernel A0 (tiny): pre-convert W_ih to scaled bf16 B-fragments + biases.
// ---------------------------------------------------------------------------
__global__ __launch_bounds__(128) void prep_wih(
    const float* __restrict__ W_ih, const float* __restrict__ b_ih,
    const float* __restrict__ b_hh, unsigned short* __restrict__ wbf,
    float* __restrict__ sbias) {
  const int nt = blockIdx.x;          // 0..23
  const int kf = threadIdx.x >> 6;    // 0..1
  const int L  = threadIdx.x & 63;
  const int q = L >> 4, ln = L & 15;
  const int g = nt * 16 + ln;
  const float sc = (g < 256) ? NL2E : N2L2E;
  const int k0 = kf * 32 + q * 8;
  short8 v;
#pragma unroll
  for (int i = 0; i < 8; ++i) {
    const int k = k0 + i;
    v[i] = (k < EMB) ? (short)f2bf(W_ih[(size_t)g * EMB + k] * sc) : (short)0;
  }
  *(short8*)(wbf + (size_t)((nt * 2 + kf) * 64 + L) * 8) = v;
  if (threadIdx.x < 16) {
    const int gg = nt * 16 + threadIdx.x;
    const float s2 = (gg < 256) ? NL2E : N2L2E;
    sbias[gg] = s2 * (b_ih[gg] + (gg < 256 ? b_hh[gg] : 0.f));
  }
}

// ---------------------------------------------------------------------------
// Kernel A (MFMA): gxv[v][g] = sc(g) * (b_ih[g] + (g<256 ? b_hh[g] : 0)
//                              + sum_e W_ih[g][e] * emb[v][e])
// B-fragments pre-converted by prep_wih; C staged in LDS then bulk-stored.
// ---------------------------------------------------------------------------
__global__ __launch_bounds__(256) void build_gxv(
    const float* __restrict__ emb, const unsigned short* __restrict__ wbf,
    const float* __restrict__ sbias, unsigned short* __restrict__ gxv) {
  __shared__ __align__(16) unsigned short cmat[64][392];  // 64 vocab rows, +8 pad
  const int w  = threadIdx.x >> 6;
  const int L  = threadIdx.x & 63;
  const int q  = L >> 4;
  const int ln = L & 15;
  const int vbase = blockIdx.x * 64 + w * 16;
  const int vloc  = w * 16;

  // A fragments: A[m=ln][k=q*8+i] = emb[vbase+ln][k], k zero-padded to 64
  const int vr = min(vbase + ln, VOC - 1);
  const float* arow = emb + (size_t)vr * EMB;
  short8 afr0, afr1;
  {
    float f;
#pragma unroll
    for (int i = 0; i < 8; ++i) {
      const int k = q * 8 + i; f = (k < EMB) ? arow[k] : 0.f;
      afr0[i] = (short)f2bf(f);
    }
#pragma unroll
    for (int i = 0; i < 8; ++i) {
      const int k = 32 + q * 8 + i; f = (k < EMB) ? arow[k] : 0.f;
      afr1[i] = (short)f2bf(f);
    }
  }

  for (int nt = 0; nt < 24; ++nt) {
    const short8 b0 = *(const short8*)(wbf + (size_t)((nt * 2 + 0) * 64 + L) * 8);
    const short8 b1 = *(const short8*)(wbf + (size_t)((nt * 2 + 1) * 64 + L) * 8);
    const int gg = nt * 16 + ln;
    const float bias = sbias[gg];
    float4v acc = {bias, bias, bias, bias};
    acc = __builtin_amdgcn_mfma_f32_16x16x32_bf16(afr0, b0, acc, 0, 0, 0);
    acc = __builtin_amdgcn_mfma_f32_16x16x32_bf16(afr1, b1, acc, 0, 0, 0);
#pragma unroll
    for (int r = 0; r < 4; ++r)
      cmat[vloc + q * 4 + r][gg] = f2bf(acc[r]);
  }
  __syncthreads();

  // coalesced bulk store: 64 rows x 384 ushorts = 3072 chunks of 16B
  for (int idx = threadIdx.x; idx < 3072; idx += 256) {
    const int row = idx / 48, c8 = idx - row * 48;
    const int vrow = blockIdx.x * 64 + row;
    if (vrow < VOC) {
      short8 v = *(const short8*)(&cmat[row][c8 * 8]);
      *(short8*)(gxv + (size_t)vrow * G3 + c8 * 8) = v;
    }
  }
}

// ---------------------------------------------------------------------------
// Kernel B: persistent GRU recurrence. 256 blocks = 2 GRUs x 128 chunks of
// FOUR batch columns -> 1 block/CU. Block: 256 threads = FOUR waves; wave w
// owns j in [32w, 32w+32) as TWO m-tiles (resident pre-scaled W_hh A-frags,
// 96 VGPRs). Rationale vs R7's 8 waves: all waves read IDENTICAL B-frags,
// so 4 waves halve the redundant LDS ds_read_b128 traffic (430->~240
// cyc/CU-step) while MFMA work/CU is unchanged and per-wave ILP doubles
// (6 independent 4-deep MFMA chains). Single chain per (gate,mt) with
// C-init = scaled-bhn/zero kills per-step accumulator zero-inits.
// Per lane: 2 gate elements (j0, j0+16) -> 12 transcendentals; per-CU VALU
// unchanged (half the lanes). Known risk: 1 wave/SIMD occupancy.
// ---------------------------------------------------------------------------
__global__ __launch_bounds__(256, 1) void gru_kernel(
    const int* __restrict__ x1, const int* __restrict__ x2,
    const unsigned short* __restrict__ gxv, const float* __restrict__ W_hh,
    const float* __restrict__ b_hh, float* __restrict__ fcin) {
  const int bid   = blockIdx.x;
  const int gru   = bid >> 7;         // 0..1
  const int chunk = bid & 127;        // 0..127
  const int* xs   = gru ? x2 : x1;

  const int tid = threadIdx.x;
  const int w  = tid >> 6;            // wave 0..3
  const int L  = tid & 63;            // lane
  const int q  = L >> 4;              // C-layout quad
  const int ln = L & 15;              // C-layout col group
  const int jb = w * 32;
  const int g3 = ln >> 2;             // which C register this lane consumes
  const int n  = ln & 3;              // batch column (0..3)
  const int j0 = jb + q * 4 + g3;     // this lane's hidden units: j0, j0+16
  const int ng = chunk * 4 + n;       // global batch index

  __shared__ __align__(16) unsigned short hbuf[2][512]; // h^T packed B-frags

  // --- resident A fragments (pre-scaled): afrag[gate][mtile][kf] ---
  short8 afrag[3][2][4];
#pragma unroll
  for (int t = 0; t < 3; ++t) {
    const float sc = (t < 2) ? NL2E : N2L2E;
#pragma unroll
    for (int mt = 0; mt < 2; ++mt) {
      const float* wr = W_hh + (size_t)(t * 128 + jb + mt * 16 + ln) * HID;
#pragma unroll
      for (int kf = 0; kf < 4; ++kf) {
        const int k0 = kf * 32 + q * 8;
        float4v f0 = *(const float4v*)(wr + k0);
        float4v f1 = *(const float4v*)(wr + k0 + 4);
        short8 a;
#pragma unroll
        for (int i = 0; i < 4; ++i) a[i] = (short)f2bf(f0[i] * sc);
#pragma unroll
        for (int i = 0; i < 4; ++i) a[i + 4] = (short)f2bf(f1[i] * sc);
        afrag[t][mt][kf] = a;
      }
    }
  }

  // n-gate C-init: bhn * N2L2E per C row (row r of mtile mt -> j = jb+mt*16+q*4+r)
  float4v bhn4[2];
#pragma unroll
  for (int mt = 0; mt < 2; ++mt)
#pragma unroll
    for (int r = 0; r < 4; ++r)
      bhn4[mt][r] = N2L2E * b_hh[2 * 128 + jb + mt * 16 + q * 4 + r];

  // zero both h buffers (h0 = 0)
  for (int idx = tid; idx < 1024; idx += 256) ((unsigned short*)hbuf)[idx] = 0;

  float h0 = 0.f, h1 = 0.f;

  // gx prefetch depth 2: 6 ushort loads per lane-step (2 elems x 3 gates),
  // all immediate offsets off one base pointer.
  unsigned short cr0, cr1, cz0, cz1, cn0, cn1;
  unsigned short mr0, mr1, mz0, mz1, mn0, mn1;
  {
    const unsigned short* gp = gxv + (size_t)xs[ng] * G3 + j0;
    cr0 = gp[0]; cr1 = gp[16]; cz0 = gp[128]; cz1 = gp[144]; cn0 = gp[256]; cn1 = gp[272];
    const unsigned short* gq = gxv + (size_t)xs[BATCH + ng] * G3 + j0;
    mr0 = gq[0]; mr1 = gq[16]; mz0 = gq[128]; mz1 = gq[144]; mn0 = gq[256]; mn1 = gq[272];
  }
  int tokf = xs[2 * BATCH + ng];      // token for s+2

  // h' write offsets in packed B-frag order: ((j>>3)*4 + n)*8 + (j&7)
  const int wofs0 = (((j0 >> 3) * 4 + n) << 3) + (j0 & 7);
  const int wofs1 = wofs0 + 64;       // j0+16: (j>>3)+2 -> +2*4*8
  // B-frag read offset: cols >=4 alias col&3 (LDS same-address broadcast)
  const int rofs = ((q * 4 + n) << 3);

  const bool selA = (ln & 4) != 0;    // g3 bit 0
  const bool selB = (ln & 8) != 0;    // g3 bit 1

  __syncthreads();

  for (int s = 0; s < S_LEN; ++s) {
    // issue gx for step s+2 (stays in flight across two lgkm-only barriers)
    unsigned short fr0, fr1, fz0, fz1, fn0, fn1;
    {
      const unsigned short* gp = gxv + (size_t)tokf * G3 + j0;
      fr0 = gp[0]; fr1 = gp[16]; fz0 = gp[128]; fz1 = gp[144];
      fn0 = gp[256]; fn1 = gp[272];
    }
    const int s3 = (s + 3 < S_LEN) ? (s + 3) : 0;   // uniform clamp
    const int tok3 = xs[s3 * BATCH + ng];

    // B fragments from packed h^T buffer (identical for both m-tiles)
    const unsigned short* rb = hbuf[s & 1];
    short8 bfrag[4];
#pragma unroll
    for (int kf = 0; kf < 4; ++kf)
      bfrag[kf] = *(const short8*)(rb + kf * 128 + rofs);

    // 6 independent 4-deep MFMA chains (3 gates x 2 m-tiles), C-init folded
    float vsel[3][2];
#pragma unroll
    for (int t = 0; t < 3; ++t) {
#pragma unroll
      for (int mt = 0; mt < 2; ++mt) {
        float4v a = (t == 2) ? bhn4[mt] : (float4v){0.f, 0.f, 0.f, 0.f};
        a = __builtin_amdgcn_mfma_f32_16x16x32_bf16(afrag[t][mt][0], bfrag[0], a, 0, 0, 0);
        a = __builtin_amdgcn_mfma_f32_16x16x32_bf16(afrag[t][mt][1], bfrag[1], a, 0, 0, 0);
        a = __builtin_amdgcn_mfma_f32_16x16x32_bf16(afrag[t][mt][2], bfrag[2], a, 0, 0, 0);
        a = __builtin_amdgcn_mfma_f32_16x16x32_bf16(afrag[t][mt][3], bfrag[3], a, 0, 0, 0);
        // per-lane register select: r = g3 (C redundancy across ln-groups)
        const float x0 = selA ? a[1] : a[0];
        const float x1 = selA ? a[3] : a[2];
        vsel[t][mt] = selB ? x1 : x0;
      }
    }

    // gate math (args pre-scaled): 2 elems per lane
    {
      const float gr = bf2f(cr0) + vsel[0][0];
      const float gz = bf2f(cz0) + vsel[1][0];
      const float rg = __builtin_amdgcn_rcpf(1.f + __builtin_amdgcn_exp2f(gr));
      const float zg = __builtin_amdgcn_rcpf(1.f + __builtin_amdgcn_exp2f(gz));
      const float pre = bf2f(cn0) + rg * vsel[2][0];
      const float sg  = __builtin_amdgcn_rcpf(1.f + __builtin_amdgcn_exp2f(pre));
      const float nn  = 2.f * sg - 1.f;              // tanh
      h0 = zg * (h0 - nn) + nn;
    }
    {
      const float gr = bf2f(cr1) + vsel[0][1];
      const float gz = bf2f(cz1) + vsel[1][1];
      const float rg = __builtin_amdgcn_rcpf(1.f + __builtin_amdgcn_exp2f(gr));
      const float zg = __builtin_amdgcn_rcpf(1.f + __builtin_amdgcn_exp2f(gz));
      const float pre = bf2f(cn1) + rg * vsel[2][1];
      const float sg  = __builtin_amdgcn_rcpf(1.f + __builtin_amdgcn_exp2f(pre));
      const float nn  = 2.f * sg - 1.f;              // tanh
      h1 = zg * (h1 - nn) + nn;
    }

    // write h' as bf16 (round-half-up): two b16 writes per lane
    unsigned short* wbuf = hbuf[(s + 1) & 1];
    wbuf[wofs0] = (unsigned short)((fbits(h0) + 0x8000u) >> 16);
    wbuf[wofs1] = (unsigned short)((fbits(h1) + 0x8000u) >> 16);

    // LDS-only barrier: do NOT drain vmcnt — gx prefetches stay in flight
    asm volatile("s_waitcnt lgkmcnt(0)\n\ts_barrier" ::: "memory");

    cr0 = mr0; cr1 = mr1; cz0 = mz0; cz1 = mz1; cn0 = mn0; cn1 = mn1;
    mr0 = fr0; mr1 = fr1; mz0 = fz0; mz1 = fz1; mn0 = fn0; mn1 = fn1;
    tokf = tok3;
  }

  // final h -> fcin[b][gru*128 + j]
  fcin[(size_t)ng * 256 + gru * 128 + j0]      = h0;
  fcin[(size_t)ng * 256 + gru * 128 + j0 + 16] = h1;
}

// ---------------------------------------------------------------------------
// Kernel C: out[b] = sigmoid(b2 + W2 . relu(b1 + W1 . fcin[b]))
// ---------------------------------------------------------------------------
__global__ __launch_bounds__(128) void head_kernel(
    const float* __restrict__ fcin, const float* __restrict__ W1,
    const float* __restrict__ b1, const float* __restrict__ W2,
    const float* __restrict__ b2, float* __restrict__ out) {
  __shared__ float fc[256];
  __shared__ float part[2];
  const int b = blockIdx.x, t = threadIdx.x;
  fc[t]       = fcin[(size_t)b * 256 + t];
  fc[t + 128] = fcin[(size_t)b * 256 + t + 128];
  __syncthreads();

  float acc = b1[t];
#pragma unroll 8
  for (int k = 0; k < 256; ++k) acc += W1[t * 256 + k] * fc[k];
  const float hid = fmaxf(acc, 0.f);

  float v = hid * W2[t];
#pragma unroll
  for (int o = 32; o > 0; o >>= 1) v += __shfl_xor(v, o, 64);
  if ((t & 63) == 0) part[t >> 6] = v;
  __syncthreads();
  if (t == 0) {
    const float s = part[0] + part[1] + b2[0];
    out[b] = fast_sig(s);
  }
}

// ---------------------------------------------------------------------------
extern "C" void kernel_launch(void* const* d_in, const int* in_sizes, int n_in,
                              void* d_out, int out_size, void* d_ws, size_t ws_size,
                              hipStream_t stream) {
  const int*   x1   = (const int*)d_in[0];
  const int*   x2   = (const int*)d_in[1];
  const float* emb  = (const float*)d_in[2];
  const float* W_ih = (const float*)d_in[3];
  const float* W_hh = (const float*)d_in[4];
  const float* b_ih = (const float*)d_in[5];
  const float* b_hh = (const float*)d_in[6];
  const float* W1   = (const float*)d_in[7];
  const float* b1   = (const float*)d_in[8];
  const float* W2   = (const float*)d_in[9];
  const float* b2   = (const float*)d_in[10];
  float* out = (float*)d_out;

  char* ws = (char*)d_ws;
  unsigned short* gxv  = (unsigned short*)ws;                     // 38.4 MB
  float*          fcin = (float*)(ws + (size_t)VOC * G3 * 2);     // 512 KB
  unsigned short* wbf  = (unsigned short*)(ws + (size_t)VOC * G3 * 2 + 524288); // 48 KB
  float*          sbias= (float*)(ws + (size_t)VOC * G3 * 2 + 524288 + 49152);  // 1.5 KB

  prep_wih<<<24, 128, 0, stream>>>(W_ih, b_ih, b_hh, wbf, sbias);
  build_gxv<<<(VOC + 63) / 64, 256, 0, stream>>>(emb, wbf, sbias, gxv);
  gru_kernel<<<256, 256, 0, stream>>>(x1, x2, gxv, W_hh, b_hh, fcin);
  head_kernel<<<512, 128, 0, stream>>>(fcin, W1, b1, W2, b2, out);
}

// Round 10
// 409.736 us; speedup vs baseline: 1.0232x; 1.0232x over previous
//
#include <hip/hip_runtime.h>
#include <hip/hip_bf16.h>
#include <stdint.h>

#define S_LEN 512
#define BATCH 512
#define HID   128
#define G3    384
#define EMB   50
#define VOC   50000

// sigmoid(x) = rcp(1 + exp2(x * -log2(e))); tanh(y) = 2*sigmoid(2y)-1.
// W_hh/gxv rows are PRE-SCALED: r,z rows by NL2E, n rows by N2L2E.
#define NL2E  (-1.4426950408889634f)
#define N2L2E (-2.8853900817779268f)

typedef __attribute__((ext_vector_type(8))) short short8;
typedef __attribute__((ext_vector_type(4))) float float4v;
typedef __attribute__((ext_vector_type(2))) uint32_t uint2v;

__device__ inline unsigned short f2bf(float f) {
  union { float f; uint32_t u; } v; v.f = f;
  uint32_t u = v.u;
  u += 0x7fffu + ((u >> 16) & 1u);   // RNE
  return (unsigned short)(u >> 16);
}
__device__ inline float bf2f(unsigned short h) {
  union { uint32_t u; float f; } v; v.u = ((uint32_t)h) << 16;
  return v.f;
}
__device__ inline float bitsf(uint32_t u) {
  union { uint32_t u; float f; } v; v.u = u; return v.f;
}
__device__ inline uint32_t fbits(float f) {
  union { float f; uint32_t u; } v; v.f = f; return v.u;
}
__device__ inline float fast_sig(float x) {
  return __builtin_amdgcn_rcpf(1.f + __expf(-x));
}

// ---------------------------------------------------------------------------
// Kernel A0 (tiny): pre-convert W_ih to scaled bf16 B-fragments + biases.
// ---------------------------------------------------------------------------
__global__ __launch_bounds__(128) void prep_wih(
    const float* __restrict__ W_ih, const float* __restrict__ b_ih,
    const float* __restrict__ b_hh, unsigned short* __restrict__ wbf,
    float* __restrict__ sbias) {
  const int nt = blockIdx.x;          // 0..23
  const int kf = threadIdx.x >> 6;    // 0..1
  const int L  = threadIdx.x & 63;
  const int q = L >> 4, ln = L & 15;
  const int g = nt * 16 + ln;
  const float sc = (g < 256) ? NL2E : N2L2E;
  const int k0 = kf * 32 + q * 8;
  short8 v;
#pragma unroll
  for (int i = 0; i < 8; ++i) {
    const int k = k0 + i;
    v[i] = (k < EMB) ? (short)f2bf(W_ih[(size_t)g * EMB + k] * sc) : (short)0;
  }
  *(short8*)(wbf + (size_t)((nt * 2 + kf) * 64 + L) * 8) = v;
  if (threadIdx.x < 16) {
    const int gg = nt * 16 + threadIdx.x;
    const float s2 = (gg < 256) ? NL2E : N2L2E;
    sbias[gg] = s2 * (b_ih[gg] + (gg < 256 ? b_hh[gg] : 0.f));
  }
}

// ---------------------------------------------------------------------------
// Kernel A (MFMA): gxv[v][g] = sc(g) * (b_ih[g] + (g<256 ? b_hh[g] : 0)
//                              + sum_e W_ih[g][e] * emb[v][e])
// B-fragments pre-converted by prep_wih; C staged in LDS then bulk-stored.
// ---------------------------------------------------------------------------
__global__ __launch_bounds__(256) void build_gxv(
    const float* __restrict__ emb, const unsigned short* __restrict__ wbf,
    const float* __restrict__ sbias, unsigned short* __restrict__ gxv) {
  __shared__ __align__(16) unsigned short cmat[64][392];  // 64 vocab rows, +8 pad
  const int w  = threadIdx.x >> 6;
  const int L  = threadIdx.x & 63;
  const int q  = L >> 4;
  const int ln = L & 15;
  const int vbase = blockIdx.x * 64 + w * 16;
  const int vloc  = w * 16;

  // A fragments: A[m=ln][k=q*8+i] = emb[vbase+ln][k], k zero-padded to 64
  const int vr = min(vbase + ln, VOC - 1);
  const float* arow = emb + (size_t)vr * EMB;
  short8 afr0, afr1;
  {
    float f;
#pragma unroll
    for (int i = 0; i < 8; ++i) {
      const int k = q * 8 + i; f = (k < EMB) ? arow[k] : 0.f;
      afr0[i] = (short)f2bf(f);
    }
#pragma unroll
    for (int i = 0; i < 8; ++i) {
      const int k = 32 + q * 8 + i; f = (k < EMB) ? arow[k] : 0.f;
      afr1[i] = (short)f2bf(f);
    }
  }

  for (int nt = 0; nt < 24; ++nt) {
    const short8 b0 = *(const short8*)(wbf + (size_t)((nt * 2 + 0) * 64 + L) * 8);
    const short8 b1 = *(const short8*)(wbf + (size_t)((nt * 2 + 1) * 64 + L) * 8);
    const int gg = nt * 16 + ln;
    const float bias = sbias[gg];
    float4v acc = {bias, bias, bias, bias};
    acc = __builtin_amdgcn_mfma_f32_16x16x32_bf16(afr0, b0, acc, 0, 0, 0);
    acc = __builtin_amdgcn_mfma_f32_16x16x32_bf16(afr1, b1, acc, 0, 0, 0);
#pragma unroll
    for (int r = 0; r < 4; ++r)
      cmat[vloc + q * 4 + r][gg] = f2bf(acc[r]);
  }
  __syncthreads();

  // coalesced bulk store: 64 rows x 384 ushorts = 3072 chunks of 16B
  for (int idx = threadIdx.x; idx < 3072; idx += 256) {
    const int row = idx / 48, c8 = idx - row * 48;
    const int vrow = blockIdx.x * 64 + row;
    if (vrow < VOC) {
      short8 v = *(const short8*)(&cmat[row][c8 * 8]);
      *(short8*)(gxv + (size_t)vrow * G3 + c8 * 8) = v;
    }
  }
}

// ---------------------------------------------------------------------------
// Kernel B: persistent GRU recurrence. 256 blocks = 2 GRUs x 128 chunks of
// FOUR batch columns -> 1 block/CU. 8 waves (R7 schedule — 2 waves/SIMD is
// required for latency hiding; R9's 4-wave variant regressed). Wave w owns
// j in [16w,16w+16); 12 mfma_f32_16x16x32_bf16 per wave-step; B cols 4..15
// broadcast-alias cols 0..3 -> C 4x redundant -> per-lane cndmask select.
// R10 change vs R7: gx for r/z gates loaded as ONE dwordx2 per gate (the
// lane's 4 contiguous C-rows jb+q*4..+3) and used as the MFMA C-INIT of a
// single 4-deep chain — removes 24 acc zero-init movs + 12 combine adds +
// post-MFMA gx adds per lane-step and shortens the serial chain (select
// feeds exp2 directly). Load count unchanged (3/lane-step).
// ---------------------------------------------------------------------------
__global__ __launch_bounds__(512) void gru_kernel(
    const int* __restrict__ x1, const int* __restrict__ x2,
    const unsigned short* __restrict__ gxv, const float* __restrict__ W_hh,
    const float* __restrict__ b_hh, float* __restrict__ fcin) {
  const int bid   = blockIdx.x;
  const int gru   = bid >> 7;         // 0..1
  const int chunk = bid & 127;        // 0..127
  const int* xs   = gru ? x2 : x1;

  const int tid = threadIdx.x;
  const int w  = tid >> 6;            // wave 0..7
  const int L  = tid & 63;            // lane
  const int q  = L >> 4;              // C-layout quad
  const int ln = L & 15;              // C-layout col group
  const int jb = w * 16;
  const int g3 = ln >> 2;             // which C register this lane consumes
  const int n  = ln & 3;              // batch column (0..3)
  const int jb4 = jb + q * 4;         // this lane's 4 C-rows: jb4..jb4+3
  const int j  = jb4 + g3;            // this lane's hidden unit
  const int ng = chunk * 4 + n;       // global batch index

  __shared__ __align__(16) unsigned short hbuf[2][512]; // h^T packed B-frags

  // --- resident A fragments (pre-scaled): A[m=ln][k=q*8+i] per 16x16x32 ---
  short8 afrag[3][4];
#pragma unroll
  for (int t = 0; t < 3; ++t) {
    const float sc = (t < 2) ? NL2E : N2L2E;
    const float* wr = W_hh + (size_t)(t * 128 + jb + ln) * HID;
#pragma unroll
    for (int kf = 0; kf < 4; ++kf) {
      const int k0 = kf * 32 + q * 8;
      float4v f0 = *(const float4v*)(wr + k0);
      float4v f1 = *(const float4v*)(wr + k0 + 4);
      short8 a;
#pragma unroll
      for (int i = 0; i < 4; ++i) a[i] = (short)f2bf(f0[i] * sc);
#pragma unroll
      for (int i = 0; i < 4; ++i) a[i + 4] = (short)f2bf(f1[i] * sc);
      afrag[t][kf] = a;
    }
  }

  // n-gate C-init: bhn * N2L2E per C row (row r -> j = jb4 + r)
  float4v bhn4;
#pragma unroll
  for (int r = 0; r < 4; ++r) bhn4[r] = N2L2E * b_hh[2 * 128 + jb4 + r];

  // zero both h buffers (h0 = 0)
  for (int idx = tid; idx < 1024; idx += 512) ((unsigned short*)hbuf)[idx] = 0;

  float h = 0.f;

  // gx prefetch depth 2: per step, r/z gates = one dwordx2 each (4 bf16 =
  // this lane's 4 C-rows), n gate = one ushort (only the needed element).
  uint2v cR, cZ, mR, mZ;
  unsigned short cN, mN;
  {
    const unsigned short* gp = gxv + (size_t)xs[ng] * G3 + jb4;
    cR = *(const uint2v*)(gp);
    cZ = *(const uint2v*)(gp + 128);
    cN = gp[256 + g3];
    const unsigned short* gq = gxv + (size_t)xs[BATCH + ng] * G3 + jb4;
    mR = *(const uint2v*)(gq);
    mZ = *(const uint2v*)(gq + 128);
    mN = gq[256 + g3];
  }
  int tokf = xs[2 * BATCH + ng];      // token for s+2

  // h' write offset in packed B-frag order: ((j>>3)*4 + n)*8 + (j&7)
  const int wofs = (((j >> 3) * 4 + n) << 3) + (j & 7);
  // B-frag read offset: cols >=4 alias col&3 (LDS same-address broadcast)
  const int rofs = ((q * 4 + n) << 3);

  const bool selA = (ln & 4) != 0;    // g3 bit 0
  const bool selB = (ln & 8) != 0;    // g3 bit 1

  __syncthreads();

  for (int s = 0; s < S_LEN; ++s) {
    // issue gx for step s+2 (stays in flight across two lgkm-only barriers)
    uint2v fR, fZ;
    unsigned short fN;
    {
      const unsigned short* gp = gxv + (size_t)tokf * G3 + jb4;
      fR = *(const uint2v*)(gp);
      fZ = *(const uint2v*)(gp + 128);
      fN = gp[256 + g3];
    }
    const int s3 = (s + 3 < S_LEN) ? (s + 3) : 0;   // uniform clamp
    const int tok3 = xs[s3 * BATCH + ng];

    // B fragments from packed h^T buffer
    const unsigned short* rb = hbuf[s & 1];
    short8 bfrag[4];
#pragma unroll
    for (int kf = 0; kf < 4; ++kf)
      bfrag[kf] = *(const short8*)(rb + kf * 128 + rofs);

    // C-inits: r/z = gx rows (bf16->fp32, 4 cvts each); n = scaled bhn
    float4v aR, aZ, aN;
    aR[0] = bitsf(cR[0] << 16); aR[1] = bitsf(cR[0] & 0xffff0000u);
    aR[2] = bitsf(cR[1] << 16); aR[3] = bitsf(cR[1] & 0xffff0000u);
    aZ[0] = bitsf(cZ[0] << 16); aZ[1] = bitsf(cZ[0] & 0xffff0000u);
    aZ[2] = bitsf(cZ[1] << 16); aZ[3] = bitsf(cZ[1] & 0xffff0000u);
    aN = bhn4;

    // single 4-deep MFMA chain per gate (3 independent chains)
#pragma unroll
    for (int kf = 0; kf < 4; ++kf)
      aR = __builtin_amdgcn_mfma_f32_16x16x32_bf16(afrag[0][kf], bfrag[kf], aR, 0, 0, 0);
#pragma unroll
    for (int kf = 0; kf < 4; ++kf)
      aZ = __builtin_amdgcn_mfma_f32_16x16x32_bf16(afrag[1][kf], bfrag[kf], aZ, 0, 0, 0);
#pragma unroll
    for (int kf = 0; kf < 4; ++kf)
      aN = __builtin_amdgcn_mfma_f32_16x16x32_bf16(afrag[2][kf], bfrag[kf], aN, 0, 0, 0);

    // per-lane register select r = g3 (C 4x redundant across ln-groups);
    // r/z selections are COMPLETE pre-activations (gx folded in C-init)
    const float grx0 = selA ? aR[1] : aR[0];
    const float grx1 = selA ? aR[3] : aR[2];
    const float gr   = selB ? grx1 : grx0;
    const float gzx0 = selA ? aZ[1] : aZ[0];
    const float gzx1 = selA ? aZ[3] : aZ[2];
    const float gz   = selB ? gzx1 : gzx0;
    const float gnx0 = selA ? aN[1] : aN[0];
    const float gnx1 = selA ? aN[3] : aN[2];
    const float ghn  = selB ? gnx1 : gnx0;

    // gate math (args pre-scaled by -log2e / -2log2e): 1 elem per lane
    const float rg = __builtin_amdgcn_rcpf(1.f + __builtin_amdgcn_exp2f(gr));
    const float zg = __builtin_amdgcn_rcpf(1.f + __builtin_amdgcn_exp2f(gz));
    const float pre = bf2f(cN) + rg * ghn;           // gx_n outside r*(...)
    const float sg  = __builtin_amdgcn_rcpf(1.f + __builtin_amdgcn_exp2f(pre));
    const float nn  = 2.f * sg - 1.f;                // tanh
    h = zg * (h - nn) + nn;

    // write h' as bf16 (round-half-up): one b16 write, all 64 lanes
    hbuf[(s + 1) & 1][wofs] = (unsigned short)((fbits(h) + 0x8000u) >> 16);

    // LDS-only barrier: do NOT drain vmcnt — gx prefetches stay in flight
    asm volatile("s_waitcnt lgkmcnt(0)\n\ts_barrier" ::: "memory");

    cR = mR; cZ = mZ; cN = mN;
    mR = fR; mZ = fZ; mN = fN;
    tokf = tok3;
  }

  // final h -> fcin[b][gru*128 + j]
  fcin[(size_t)ng * 256 + gru * 128 + j] = h;
}

// ---------------------------------------------------------------------------
// Kernel C: out[b] = sigmoid(b2 + W2 . relu(b1 + W1 . fcin[b]))
// ---------------------------------------------------------------------------
__global__ __launch_bounds__(128) void head_kernel(
    const float* __restrict__ fcin, const float* __restrict__ W1,
    const float* __restrict__ b1, const float* __restrict__ W2,
    const float* __restrict__ b2, float* __restrict__ out) {
  __shared__ float fc[256];
  __shared__ float part[2];
  const int b = blockIdx.x, t = threadIdx.x;
  fc[t]       = fcin[(size_t)b * 256 + t];
  fc[t + 128] = fcin[(size_t)b * 256 + t + 128];
  __syncthreads();

  float acc = b1[t];
#pragma unroll 8
  for (int k = 0; k < 256; ++k) acc += W1[t * 256 + k] * fc[k];
  const float hid = fmaxf(acc, 0.f);

  float v = hid * W2[t];
#pragma unroll
  for (int o = 32; o > 0; o >>= 1) v += __shfl_xor(v, o, 64);
  if ((t & 63) == 0) part[t >> 6] = v;
  __syncthreads();
  if (t == 0) {
    const float s = part[0] + part[1] + b2[0];
    out[b] = fast_sig(s);
  }
}

// ---------------------------------------------------------------------------
extern "C" void kernel_launch(void* const* d_in, const int* in_sizes, int n_in,
                              void* d_out, int out_size, void* d_ws, size_t ws_size,
                              hipStream_t stream) {
  const int*   x1   = (const int*)d_in[0];
  const int*   x2   = (const int*)d_in[1];
  const float* emb  = (const float*)d_in[2];
  const float* W_ih = (const float*)d_in[3];
  const float* W_hh = (const float*)d_in[4];
  const float* b_ih = (const float*)d_in[5];
  const float* b_hh = (const float*)d_in[6];
  const float* W1   = (const float*)d_in[7];
  const float* b1   = (const float*)d_in[8];
  const float* W2   = (const float*)d_in[9];
  const float* b2   = (const float*)d_in[10];
  float* out = (float*)d_out;

  char* ws = (char*)d_ws;
  unsigned short* gxv  = (unsigned short*)ws;                     // 38.4 MB
  float*          fcin = (float*)(ws + (size_t)VOC * G3 * 2);     // 512 KB
  unsigned short* wbf  = (unsigned short*)(ws + (size_t)VOC * G3 * 2 + 524288); // 48 KB
  float*          sbias= (float*)(ws + (size_t)VOC * G3 * 2 + 524288 + 49152);  // 1.5 KB

  prep_wih<<<24, 128, 0, stream>>>(W_ih, b_ih, b_hh, wbf, sbias);
  build_gxv<<<(VOC + 63) / 64, 256, 0, stream>>>(emb, wbf, sbias, gxv);
  gru_kernel<<<256, 512, 0, stream>>>(x1, x2, gxv, W_hh, b_hh, fcin);
  head_kernel<<<512, 128, 0, stream>>>(fcin, W1, b1, W2, b2, out);
}

// Round 12
// 343.089 us; speedup vs baseline: 1.2220x; 1.1943x over previous
//
#include <hip/hip_runtime.h>
#include <hip/hip_bf16.h>
#include <stdint.h>

#define S_LEN 512
#define BATCH 512
#define HID   128
#define G3    384
#define EMB   50
#define VOC   50000

// sigmoid(x) = rcp(1 + exp2(x * -log2(e))); tanh(y) = 2*sigmoid(2y)-1.
// W_hh/gxv rows are PRE-SCALED: r,z rows by NL2E, n rows by N2L2E.
#define NL2E  (-1.4426950408889634f)
#define N2L2E (-2.8853900817779268f)

typedef __attribute__((ext_vector_type(8))) short short8;
typedef __attribute__((ext_vector_type(4))) float float4v;
typedef __attribute__((ext_vector_type(2))) uint32_t uint2v;

__device__ inline unsigned short f2bf(float f) {
  union { float f; uint32_t u; } v; v.f = f;
  uint32_t u = v.u;
  u += 0x7fffu + ((u >> 16) & 1u);   // RNE
  return (unsigned short)(u >> 16);
}
__device__ inline float bf2f(unsigned short h) {
  union { uint32_t u; float f; } v; v.u = ((uint32_t)h) << 16;
  return v.f;
}
__device__ inline uint32_t fbits(float f) {
  union { float f; uint32_t u; } v; v.f = f; return v.u;
}
__device__ inline float fast_sig(float x) {
  return __builtin_amdgcn_rcpf(1.f + __expf(-x));
}

// ---------------------------------------------------------------------------
// Kernel A0 (tiny): pre-convert W_ih to scaled bf16 B-fragments + biases.
// ---------------------------------------------------------------------------
__global__ __launch_bounds__(128) void prep_wih(
    const float* __restrict__ W_ih, const float* __restrict__ b_ih,
    const float* __restrict__ b_hh, unsigned short* __restrict__ wbf,
    float* __restrict__ sbias) {
  const int nt = blockIdx.x;          // 0..23
  const int kf = threadIdx.x >> 6;    // 0..1
  const int L  = threadIdx.x & 63;
  const int q = L >> 4, ln = L & 15;
  const int g = nt * 16 + ln;
  const float sc = (g < 256) ? NL2E : N2L2E;
  const int k0 = kf * 32 + q * 8;
  short8 v;
#pragma unroll
  for (int i = 0; i < 8; ++i) {
    const int k = k0 + i;
    v[i] = (k < EMB) ? (short)f2bf(W_ih[(size_t)g * EMB + k] * sc) : (short)0;
  }
  *(short8*)(wbf + (size_t)((nt * 2 + kf) * 64 + L) * 8) = v;
  if (threadIdx.x < 16) {
    const int gg = nt * 16 + threadIdx.x;
    const float s2 = (gg < 256) ? NL2E : N2L2E;
    sbias[gg] = s2 * (b_ih[gg] + (gg < 256 ? b_hh[gg] : 0.f));
  }
}

// ---------------------------------------------------------------------------
// Kernel A (MFMA): gxv[v][g] = sc(g) * (b_ih[g] + (g<256 ? b_hh[g] : 0)
//                              + sum_e W_ih[g][e] * emb[v][e])
// R12: A-frag setup via float4 vector loads + lane masks (scalar fallback
// only for the final block, which would read past emb); depth-1 software
// pipeline on the wbf/sbias loads (no barrier in loop -> safe).
// ---------------------------------------------------------------------------
__global__ __launch_bounds__(256) void build_gxv(
    const float* __restrict__ emb, const unsigned short* __restrict__ wbf,
    const float* __restrict__ sbias, unsigned short* __restrict__ gxv) {
  __shared__ __align__(16) unsigned short cmat[64][392];  // 64 vocab rows, +8 pad
  const int w  = threadIdx.x >> 6;
  const int L  = threadIdx.x & 63;
  const int q  = L >> 4;
  const int ln = L & 15;
  const int vbase = blockIdx.x * 64 + w * 16;
  const int vloc  = w * 16;
  const int nblocks = (VOC + 63) / 64;

  // A fragments: A[m=ln][k=q*8+i] = emb[vbase+ln][k], k zero-padded to 64
  const int vr = min(vbase + ln, VOC - 1);
  const float* arow = emb + (size_t)vr * EMB;
  short8 afr0, afr1;
  if (blockIdx.x != nblocks - 1) {
    // vector path: reads arow[0..63]; rows here have vr <= 49983, so the
    // overread stays far inside emb (next rows' data, masked to zero below)
    const float4v x0 = *(const float4v*)(arow + q * 8);
    const float4v x1 = *(const float4v*)(arow + q * 8 + 4);
    const float4v y0 = *(const float4v*)(arow + 32 + q * 8);
    const float4v y1 = *(const float4v*)(arow + 32 + q * 8 + 4);
#pragma unroll
    for (int i = 0; i < 4; ++i) {
      afr0[i]     = (short)f2bf(x0[i]);
      afr0[i + 4] = (short)f2bf(x1[i]);
      const int ky0 = 32 + q * 8 + i, ky1 = ky0 + 4;
      afr1[i]     = (ky0 < EMB) ? (short)f2bf(y0[i]) : (short)0;
      afr1[i + 4] = (ky1 < EMB) ? (short)f2bf(y1[i]) : (short)0;
    }
  } else {
    float f;
#pragma unroll
    for (int i = 0; i < 8; ++i) {
      const int k = q * 8 + i; f = (k < EMB) ? arow[k] : 0.f;
      afr0[i] = (short)f2bf(f);
    }
#pragma unroll
    for (int i = 0; i < 8; ++i) {
      const int k = 32 + q * 8 + i; f = (k < EMB) ? arow[k] : 0.f;
      afr1[i] = (short)f2bf(f);
    }
  }

  // depth-1 pipelined main loop
  short8 b0 = *(const short8*)(wbf + (size_t)(0 * 64 + L) * 8);
  short8 b1 = *(const short8*)(wbf + (size_t)(1 * 64 + L) * 8);
  float bias = sbias[ln];
  for (int nt = 0; nt < 24; ++nt) {
    short8 nb0, nb1; float nbias;
    if (nt < 23) {
      nb0 = *(const short8*)(wbf + (size_t)((nt * 2 + 2) * 64 + L) * 8);
      nb1 = *(const short8*)(wbf + (size_t)((nt * 2 + 3) * 64 + L) * 8);
      nbias = sbias[nt * 16 + 16 + ln];
    }
    const int gg = nt * 16 + ln;
    float4v acc = {bias, bias, bias, bias};
    acc = __builtin_amdgcn_mfma_f32_16x16x32_bf16(afr0, b0, acc, 0, 0, 0);
    acc = __builtin_amdgcn_mfma_f32_16x16x32_bf16(afr1, b1, acc, 0, 0, 0);
#pragma unroll
    for (int r = 0; r < 4; ++r)
      cmat[vloc + q * 4 + r][gg] = f2bf(acc[r]);
    b0 = nb0; b1 = nb1; bias = nbias;
  }
  __syncthreads();

  // coalesced bulk store: 64 rows x 384 ushorts = 3072 chunks of 16B
  for (int idx = threadIdx.x; idx < 3072; idx += 256) {
    const int row = idx / 48, c8 = idx - row * 48;
    const int vrow = blockIdx.x * 64 + row;
    if (vrow < VOC) {
      short8 v = *(const short8*)(&cmat[row][c8 * 8]);
      *(short8*)(gxv + (size_t)vrow * G3 + c8 * 8) = v;
    }
  }
}

// ---------------------------------------------------------------------------
// Kernel B: persistent GRU recurrence — EXACT R7 revert (proven 282 us).
// 256 blocks = 2 GRUs x 128 chunks of FOUR batch columns -> 1 block/CU.
// 8 waves; wave w owns j in [16w,16w+16); 12 mfma_f32_16x16x32_bf16 per
// wave-step; B cols 4..15 broadcast-alias cols 0..3 -> C 4x redundant ->
// per-lane cndmask select; 1 gate elem/lane (6 transcendentals); h fp32;
// h' one ds_write_b16; lgkm-only barrier; depth-2 gx prefetch.
// Do NOT touch this loop: R8 (plane split + unroll2), R9 (4 waves),
// R10 (gx as MFMA C-init), R11 (i8) all regressed or failed precision.
// ---------------------------------------------------------------------------
__global__ __launch_bounds__(512) void gru_kernel(
    const int* __restrict__ x1, const int* __restrict__ x2,
    const unsigned short* __restrict__ gxv, const float* __restrict__ W_hh,
    const float* __restrict__ b_hh, float* __restrict__ fcin) {
  const int bid   = blockIdx.x;
  const int gru   = bid >> 7;         // 0..1
  const int chunk = bid & 127;        // 0..127
  const int* xs   = gru ? x2 : x1;

  const int tid = threadIdx.x;
  const int w  = tid >> 6;            // wave 0..7
  const int L  = tid & 63;            // lane
  const int q  = L >> 4;              // C-layout quad
  const int ln = L & 15;              // C-layout col group
  const int jb = w * 16;
  const int g3 = ln >> 2;             // which C register this lane consumes
  const int n  = ln & 3;              // batch column (0..3)
  const int j  = jb + q * 4 + g3;     // this lane's hidden unit
  const int ng = chunk * 4 + n;       // global batch index

  __shared__ __align__(16) unsigned short hbuf[2][512]; // h^T packed B-frags

  // --- resident A fragments (pre-scaled): A[m=ln][k=q*8+i] per 16x16x32 ---
  short8 afrag[3][4];
#pragma unroll
  for (int t = 0; t < 3; ++t) {
    const float sc = (t < 2) ? NL2E : N2L2E;
    const float* wr = W_hh + (size_t)(t * 128 + jb + ln) * HID;
#pragma unroll
    for (int kf = 0; kf < 4; ++kf) {
      const int k0 = kf * 32 + q * 8;
      float4v f0 = *(const float4v*)(wr + k0);
      float4v f1 = *(const float4v*)(wr + k0 + 4);
      short8 a;
#pragma unroll
      for (int i = 0; i < 4; ++i) a[i] = (short)f2bf(f0[i] * sc);
#pragma unroll
      for (int i = 0; i < 4; ++i) a[i + 4] = (short)f2bf(f1[i] * sc);
      afrag[t][kf] = a;
    }
  }

  // n-gate C-init: bhn * N2L2E per C row (row r -> j = jb + q*4 + r)
  float4v bhn4;
#pragma unroll
  for (int r = 0; r < 4; ++r) bhn4[r] = N2L2E * b_hh[2 * 128 + jb + q * 4 + r];

  // zero both h buffers (h0 = 0)
  for (int idx = tid; idx < 1024; idx += 512) ((unsigned short*)hbuf)[idx] = 0;

  float h = 0.f;

  // gx prefetch depth 2: 3 bf16 scalars per lane-step
  unsigned short cr, cz, cn, mr, mz, mn;
  {
    const unsigned short* gp = gxv + (size_t)xs[ng] * G3;
    cr = gp[j]; cz = gp[128 + j]; cn = gp[256 + j];
    const unsigned short* gq = gxv + (size_t)xs[BATCH + ng] * G3;
    mr = gq[j]; mz = gq[128 + j]; mn = gq[256 + j];
  }
  int tokf = xs[2 * BATCH + ng];      // token for s+2

  // h' write offset in packed B-frag order: ((j>>3)*4 + n)*8 + (j&7)
  const int wofs = (((j >> 3) * 4 + n) << 3) + (j & 7);
  // B-frag read offset: cols >=4 alias col&3 (LDS same-address broadcast)
  const int rofs = ((q * 4 + n) << 3);

  const bool selA = (ln & 4) != 0;    // g3 bit 0
  const bool selB = (ln & 8) != 0;    // g3 bit 1

  __syncthreads();

  for (int s = 0; s < S_LEN; ++s) {
    // issue gx for step s+2 (stays in flight across two lgkm-only barriers)
    unsigned short fr, fz, fn;
    {
      const unsigned short* gp = gxv + (size_t)tokf * G3;
      fr = gp[j]; fz = gp[128 + j]; fn = gp[256 + j];
    }
    const int s3 = (s + 3 < S_LEN) ? (s + 3) : 0;   // uniform clamp
    const int tok3 = xs[s3 * BATCH + ng];

    // B fragments from packed h^T buffer
    const unsigned short* rb = hbuf[s & 1];
    short8 bfrag[4];
#pragma unroll
    for (int kf = 0; kf < 4; ++kf)
      bfrag[kf] = *(const short8*)(rb + kf * 128 + rofs);

    // 2 independent 2-deep MFMA chains per gate; n-gate C-init = scaled bhn
    float vsel[3];
#pragma unroll
    for (int t = 0; t < 3; ++t) {
      float4v a0 = (t == 2) ? bhn4 : (float4v){0.f, 0.f, 0.f, 0.f};
      float4v a1 = {0.f, 0.f, 0.f, 0.f};
      a0 = __builtin_amdgcn_mfma_f32_16x16x32_bf16(afrag[t][0], bfrag[0], a0, 0, 0, 0);
      a1 = __builtin_amdgcn_mfma_f32_16x16x32_bf16(afrag[t][1], bfrag[1], a1, 0, 0, 0);
      a0 = __builtin_amdgcn_mfma_f32_16x16x32_bf16(afrag[t][2], bfrag[2], a0, 0, 0, 0);
      a1 = __builtin_amdgcn_mfma_f32_16x16x32_bf16(afrag[t][3], bfrag[3], a1, 0, 0, 0);
      const float4v acc = a0 + a1;
      // per-lane register select: r = g3 (C redundancy across ln-groups)
      const float x0 = selA ? acc[1] : acc[0];
      const float x1 = selA ? acc[3] : acc[2];
      vsel[t] = selB ? x1 : x0;
    }

    // gate math (args pre-scaled by -log2e / -2log2e): 1 elem per lane
    const float gr = bf2f(cr) + vsel[0];
    const float gz = bf2f(cz) + vsel[1];
    const float rg = __builtin_amdgcn_rcpf(1.f + __builtin_amdgcn_exp2f(gr));
    const float zg = __builtin_amdgcn_rcpf(1.f + __builtin_amdgcn_exp2f(gz));
    const float pre = bf2f(cn) + rg * vsel[2];
    const float sg  = __builtin_amdgcn_rcpf(1.f + __builtin_amdgcn_exp2f(pre));
    const float nn  = 2.f * sg - 1.f;                // tanh
    h = zg * (h - nn) + nn;

    // write h' as bf16 (round-half-up): one b16 write, all 64 lanes
    hbuf[(s + 1) & 1][wofs] = (unsigned short)((fbits(h) + 0x8000u) >> 16);

    // LDS-only barrier: do NOT drain vmcnt — gx prefetches stay in flight
    asm volatile("s_waitcnt lgkmcnt(0)\n\ts_barrier" ::: "memory");

    cr = mr; cz = mz; cn = mn;
    mr = fr; mz = fz; mn = fn;
    tokf = tok3;
  }

  // final h -> fcin[b][gru*128 + j]
  fcin[(size_t)ng * 256 + gru * 128 + j] = h;
}

// ---------------------------------------------------------------------------
// Kernel C: out[b] = sigmoid(b2 + W2 . relu(b1 + W1 . fcin[b]))
// R12: W1 row read via float4 (64 loads/thread instead of 256 scalars).
// ---------------------------------------------------------------------------
__global__ __launch_bounds__(128) void head_kernel(
    const float* __restrict__ fcin, const float* __restrict__ W1,
    const float* __restrict__ b1, const float* __restrict__ W2,
    const float* __restrict__ b2, float* __restrict__ out) {
  __shared__ __align__(16) float fc[256];
  __shared__ float part[2];
  const int b = blockIdx.x, t = threadIdx.x;
  fc[t]       = fcin[(size_t)b * 256 + t];
  fc[t + 128] = fcin[(size_t)b * 256 + t + 128];
  __syncthreads();

  float acc = b1[t];
  const float4v* wr  = (const float4v*)(W1 + (size_t)t * 256);
  const float4v* fc4 = (const float4v*)fc;
#pragma unroll 8
  for (int k = 0; k < 64; ++k) {
    const float4v wv = wr[k];
    const float4v fv = fc4[k];
    acc += wv[0] * fv[0] + wv[1] * fv[1] + wv[2] * fv[2] + wv[3] * fv[3];
  }
  const float hid = fmaxf(acc, 0.f);

  float v = hid * W2[t];
#pragma unroll
  for (int o = 32; o > 0; o >>= 1) v += __shfl_xor(v, o, 64);
  if ((t & 63) == 0) part[t >> 6] = v;
  __syncthreads();
  if (t == 0) {
    const float s = part[0] + part[1] + b2[0];
    out[b] = fast_sig(s);
  }
}

// ---------------------------------------------------------------------------
extern "C" void kernel_launch(void* const* d_in, const int* in_sizes, int n_in,
                              void* d_out, int out_size, void* d_ws, size_t ws_size,
                              hipStream_t stream) {
  const int*   x1   = (const int*)d_in[0];
  const int*   x2   = (const int*)d_in[1];
  const float* emb  = (const float*)d_in[2];
  const float* W_ih = (const float*)d_in[3];
  const float* W_hh = (const float*)d_in[4];
  const float* b_ih = (const float*)d_in[5];
  const float* b_hh = (const float*)d_in[6];
  const float* W1   = (const float*)d_in[7];
  const float* b1   = (const float*)d_in[8];
  const float* W2   = (const float*)d_in[9];
  const float* b2   = (const float*)d_in[10];
  float* out = (float*)d_out;

  char* ws = (char*)d_ws;
  unsigned short* gxv  = (unsigned short*)ws;                     // 38.4 MB
  float*          fcin = (float*)(ws + (size_t)VOC * G3 * 2);     // 512 KB
  unsigned short* wbf  = (unsigned short*)(ws + (size_t)VOC * G3 * 2 + 524288); // 48 KB
  float*          sbias= (float*)(ws + (size_t)VOC * G3 * 2 + 524288 + 49152);  // 1.5 KB

  prep_wih<<<24, 128, 0, stream>>>(W_ih, b_ih, b_hh, wbf, sbias);
  build_gxv<<<(VOC + 63) / 64, 256, 0, stream>>>(emb, wbf, sbias, gxv);
  gru_kernel<<<256, 512, 0, stream>>>(x1, x2, gxv, W_hh, b_hh, fcin);
  head_kernel<<<512, 128, 0, stream>>>(fcin, W1, b1, W2, b2, out);
}